// Round 10
// baseline (224.340 us; speedup 1.0000x reference)
//
#include <hip/hip_runtime.h>

#define NVOX 150000
#define BM 128
#define MTILES 1172         // ceil(150000/128)
#define SROW 150016         // 1172*128, column stride of h buffer
#define NCOL 320

typedef __attribute__((ext_vector_type(8))) short bf16x8;
typedef __attribute__((ext_vector_type(4))) float f32x4;

__device__ __forceinline__ unsigned short f2bf(float f) {
    unsigned u = __builtin_bit_cast(unsigned, f);
    u += 0x7fffu + ((u >> 16) & 1u);
    return (unsigned short)(u >> 16);
}

__device__ __forceinline__ void gld16(const void* g, void* l) {
    __builtin_amdgcn_global_load_lds(
        (const __attribute__((address_space(1))) unsigned int*)g,
        (__attribute__((address_space(3))) unsigned int*)l, 16, 0, 0);
}

// ------------- merged prep: features->bf16 + W3 repack (one launch fewer) -------------
__global__ void prep_all(const float* __restrict__ src, unsigned short* __restrict__ dst,
                         const float* __restrict__ w3, unsigned short* __restrict__ bt,
                         float* __restrict__ stats) {
    int bid = blockIdx.x, tid = threadIdx.x;
    if (bid < 4688) {                         // features f32 -> bf16, x8 vectorized
        int i = bid * 256 + tid;
        if (i < NVOX * 8) {
            const float* s = src + (size_t)i * 8;
            float4 a = *(const float4*)s;
            float4 b = *(const float4*)(s + 4);
            union { bf16x8 v; unsigned short u[8]; } r;
            r.u[0] = f2bf(a.x); r.u[1] = f2bf(a.y); r.u[2] = f2bf(a.z); r.u[3] = f2bf(a.w);
            r.u[4] = f2bf(b.x); r.u[5] = f2bf(b.y); r.u[6] = f2bf(b.z); r.u[7] = f2bf(b.w);
            *(bf16x8*)(dst + (size_t)i * 8) = r.v;
        } else if (i < NVOX * 8 + 8) {        // zero row for invalid/pad gathers
            bf16x8 z = {0, 0, 0, 0, 0, 0, 0, 0};
            *(bf16x8*)(dst + (size_t)i * 8) = z;
        }
    } else {                                  // W3 -> chunk-major bf16 (+ stats zero)
        int i = (bid - 4688) * 256 + tid;     // exactly 184320 threads
        int h = i / 36864;
        int rem = i - h * 36864;
        int kk = rem >> 12;
        int c = (rem >> 6) & 63;
        int o = rem & 63;
        bt[(size_t)(((h * 9 + kk) * 8) + (c >> 3)) * 512 + o * 8 + (c & 7)] = f2bf(w3[i]);
        if (i < 2 * NCOL) stats[i] = 0.f;
    }
}

// ---------------- gather-GEMM: B IN REGISTERS (LDS traffic 200->80 KB/K-step) ---------
// R9 arithmetic: per-CU K-step MFMA=1550cy but LDS=200KB=1800-2350cy (A read 4x, B 2x,
// + 56KB gld16 writes contending with compute reads). Fix: B bypasses LDS entirely -
// per-lane dwordx4 from L2-hot Bt2 into breg[2][2][5] (R2-proven pattern, parity static
// after unroll). B no longer rides the block barrier; only the A dbuf does. Pipeline:
// per iter issue stageA(kk+1)[2 gld16] + loadB(kk+1)[10 loads] = 12 vm ops ->
// vmcnt(12) retires tile kk; raw barriers; no drain in loop.
// LDS: sA dbuf 2x16K @0, idx @32768; epilogue reuses [0,87040)+SRED @88064 -> 93184.
__global__ __launch_bounds__(512, 2)
void gemm_kernel(const unsigned short* __restrict__ featB,
                 const unsigned short* __restrict__ Bt2,
                 const int* __restrict__ nbr,
                 unsigned short* __restrict__ hbuf,
                 float* __restrict__ stats,
                 float* __restrict__ partials) {
    __shared__ __align__(16) char smem[93184];
    constexpr int IDX_OFF = 32768;   // 9*128 int byte-offsets (4608 B); dead by epilogue
    constexpr int SRED_OFF = 88064;  // stats staging 640*8 B; above transpose's 87040

    int mtile = blockIdx.x;
    int m0 = mtile * BM;

    int tid = threadIdx.x;
    int w = tid >> 6, lane = tid & 63;
    int quad = lane >> 4, m16 = lane & 15;

    // ---- stage neighbor byte-offset table: sIdx[kk][row] = srow*128 ----
    for (int lin = tid; lin < BM * 9; lin += 512) {
        int row = lin / 9, kkq = lin - row * 9;
        int v = -1;
        if (m0 + row < NVOX) v = nbr[(size_t)(m0 + row) * 9 + kkq];
        *(int*)(smem + IDX_OFF + (kkq * BM + row) * 4) = ((v < 0) ? NVOX : v) * 128;
    }
    __syncthreads();

    f32x4 acc[4][5];
#pragma unroll
    for (int mt = 0; mt < 4; ++mt)
#pragma unroll
        for (int nt = 0; nt < 5; ++nt)
            acc[mt][nt] = (f32x4){0.f, 0.f, 0.f, 0.f};

    const char* fb = (const char*)featB;
    const char* bt = (const char*)Bt2;
    char* sAb[2] = {smem, smem + 16384};

    int mrow = (w >> 2) * 64;    // wave's row half (0/64)
    int cbase = (w & 3) * 80;    // wave's 80-col quarter of the 320 cols

    // gather geometry: 8 lanes per row; lane = rloc*8 + j
    int rloc = lane >> 3, j = lane & 7;
    int jx = (j ^ rloc) * 16;    // source-chunk XOR swizzle ((row&7) == rloc)

    // per-lane global B fragment byte offsets: col c -> head h=c>>6, o=c&63
    // addr = (c>>6)*73728 + kk*8192 + (ks*4+quad)*1024 + (c&63)*16
    int bOff[5];
#pragma unroll
    for (int nt = 0; nt < 5; ++nt) {
        int c = cbase + nt * 16 + m16;
        bOff[nt] = (c >> 6) * 73728 + quad * 1024 + (c & 63) * 16;
    }
    // per-lane A-frag row bases (row-major) + XOR term per ds_read
    int aRow[4];
#pragma unroll
    for (int mt = 0; mt < 4; ++mt)
        aRow[mt] = (mrow + mt * 16 + m16) * 128;
    int axor = m16 & 7;          // == row & 7 for all frag rows

    bf16x8 breg[2][2][5];        // [parity][ks][nt]; parity static after full unroll

    auto stageA = [&](int buf, int kk) {
        char* sA = sAb[buf];
        int off0 = *(const int*)(smem + IDX_OFF + (kk * BM + w * 16 + rloc) * 4);
        int off1 = *(const int*)(smem + IDX_OFF + (kk * BM + w * 16 + 8 + rloc) * 4);
        gld16(fb + off0 + jx, sA + w * 2048);          // 2 ops: 16 full rows
        gld16(fb + off1 + jx, sA + w * 2048 + 1024);
    };
    auto loadB = [&](int p, int kk) {                  // 10 per-lane dwordx4, L2-hot
#pragma unroll
        for (int nt = 0; nt < 5; ++nt) {
            breg[p][0][nt] = *(const bf16x8*)(bt + (size_t)(bOff[nt] + kk * 8192));
            breg[p][1][nt] = *(const bf16x8*)(bt + (size_t)(bOff[nt] + kk * 8192 + 4096));
        }
    };

    // prologue: tile 0 -> 12 vm ops in flight
    stageA(0, 0);
    loadB(0, 0);

#pragma unroll
    for (int kk = 0; kk < 9; ++kk) {
        const int p = kk & 1;
        if (kk < 8) {
            stageA(p ^ 1, kk + 1);                     // 2 vm ops
            loadB(p ^ 1, kk + 1);                      // 10 vm ops
            asm volatile("s_waitcnt vmcnt(12)" ::: "memory");  // tile kk retired
        } else {
            asm volatile("s_waitcnt vmcnt(0)" ::: "memory");
        }
        asm volatile("s_barrier" ::: "memory");        // raw barrier: NO drain
        __builtin_amdgcn_sched_barrier(0);             // rule 18: pin ds_read/MFMA below
        __builtin_amdgcn_s_setprio(1);
#pragma unroll
        for (int ks = 0; ks < 2; ++ks) {
            bf16x8 af[4];
            int xq = ((ks * 4 + quad) ^ axor) * 16;    // swizzled chunk within row
#pragma unroll
            for (int mt = 0; mt < 4; ++mt)
                af[mt] = *(const bf16x8*)(sAb[p] + aRow[mt] + xq);
#pragma unroll
            for (int mt = 0; mt < 4; ++mt)
#pragma unroll
                for (int nt = 0; nt < 5; ++nt)
                    acc[mt][nt] = __builtin_amdgcn_mfma_f32_16x16x32_bf16(
                        af[mt], breg[p][ks][nt], acc[mt][nt], 0, 0, 0);
        }
        __builtin_amdgcn_s_setprio(0);
        __builtin_amdgcn_sched_barrier(0);
        asm volatile("s_barrier" ::: "memory");        // sAb[p] free to restage
    }
    __builtin_amdgcn_sched_barrier(0);   // keep epilogue out of the loop region

    // ---- epilogue 1: transpose via LDS (aliases dead sA/idx), coalesced column stores
#pragma unroll
    for (int mt = 0; mt < 4; ++mt) {
#pragma unroll
        for (int nt = 0; nt < 5; ++nt) {
            int col = cbase + nt * 16 + m16;
            int row = mrow + mt * 16 + quad * 4;
            f32x4 v = acc[mt][nt];
            unsigned lo = (unsigned)f2bf(v.x) | ((unsigned)f2bf(v.y) << 16);
            unsigned hi = (unsigned)f2bf(v.z) | ((unsigned)f2bf(v.w) << 16);
            uint2 pk; pk.x = lo; pk.y = hi;
            *(uint2*)(smem + col * 272 + row * 2) = pk;   // col stride 136 ushorts
        }
    }
    __syncthreads();
#pragma unroll
    for (int it = 0; it < 20; ++it) {                  // 320 cols = 20 x (16 cols x 32 ln)
        int col = it * 16 + (tid >> 5);
        int l32 = tid & 31;
        uint2 v = *(const uint2*)(smem + col * 272 + l32 * 8);
        *(uint2*)(hbuf + (size_t)col * SROW + m0 + l32 * 4) = v;  // 256B runs
    }

    // ---- epilogue 2: BN statistics (pad/invalid rows are exact zeros) ----
    float s[5], ss[5];
#pragma unroll
    for (int nt = 0; nt < 5; ++nt) {
        float a = 0.f, b = 0.f;
#pragma unroll
        for (int mt = 0; mt < 4; ++mt) {
            f32x4 v = acc[mt][nt];
            a += v.x + v.y + v.z + v.w;
            b += v.x * v.x + v.y * v.y + v.z * v.z + v.w * v.w;
        }
        s[nt] = a; ss[nt] = b;
        s[nt] += __shfl_xor(s[nt], 16); s[nt] += __shfl_xor(s[nt], 32);
        ss[nt] += __shfl_xor(ss[nt], 16); ss[nt] += __shfl_xor(ss[nt], 32);
    }
    if (quad == 0) {   // SRED region (88064+) disjoint from transpose (<87040)
#pragma unroll
        for (int nt = 0; nt < 5; ++nt) {
            float* p = (float*)(smem + SRED_OFF + (w * 80 + nt * 16 + m16) * 8);
            p[0] = s[nt]; p[1] = ss[nt];
        }
    }
    __syncthreads();
    if (tid < NCOL) {
        int c = tid;
        int qq = c / 80, lc = c - qq * 80;   // waves qq (rows 0-63) and qq+4 (64-127)
        const float* p0 = (const float*)(smem + SRED_OFF + (qq * 80 + lc) * 8);
        const float* p1 = (const float*)(smem + SRED_OFF + ((qq + 4) * 80 + lc) * 8);
        float vsum = p0[0] + p1[0];
        float vss  = p0[1] + p1[1];
        if (partials) {
            float* pp = partials + (size_t)mtile * (2 * NCOL);
            pp[c] = vsum;                // coalesced, no atomics
            pp[NCOL + c] = vss;
        } else {
            atomicAdd(&stats[c], vsum);
            atomicAdd(&stats[NCOL + c], vss);
        }
    }
}

// ---- stats_reduce: wide (160 blocks), coalesced 128B/step reads, spread atomics ----
__global__ __launch_bounds__(256)
void stats_reduce(const float* __restrict__ partials, float* __restrict__ stats) {
    __shared__ float red[256];
    int tid = threadIdx.x;
    int cl = tid & 31, sc = tid >> 5;
    int jcol = blockIdx.x * 32 + cl;
    int ybase = blockIdx.y * 147;
    int mlo = ybase + sc * 19;
    int mhi = ybase + 147; if (mhi > MTILES) mhi = MTILES;
    int mend = mlo + 19; if (mend > mhi) mend = mhi;
    float s = 0.f;
    for (int m = mlo; m < mend; ++m)
        s += partials[(size_t)m * (2 * NCOL) + jcol];
    red[tid] = s;
    __syncthreads();
    if (tid < 32) {
        float a = red[tid];
#pragma unroll
        for (int k = 1; k < 8; ++k) a += red[k * 32 + tid];
        atomicAdd(&stats[blockIdx.x * 32 + tid], a);
    }
}

// ------- pass 2: BN + ReLU + 1x1 conv (best measured head: 4 rows/thread, coalesced
// 512B/wave-instr reads of column-major hbuf, per-head grid)
__global__ __launch_bounds__(256)
void head_kernel(const unsigned short* __restrict__ hbuf,
                 const float* __restrict__ stats,
                 const float* __restrict__ gamma, const float* __restrict__ beta,
                 const float* __restrict__ W1_0, const float* __restrict__ W1_1,
                 const float* __restrict__ W1_2, const float* __restrict__ W1_3,
                 const float* __restrict__ W1_4,
                 const float* __restrict__ b1_0, const float* __restrict__ b1_1,
                 const float* __restrict__ b1_2, const float* __restrict__ b1_3,
                 const float* __restrict__ b1_4,
                 float* __restrict__ out) {
    __shared__ float sScale[64], sShift[64], sW1[192], sB1[3];
    int h = blockIdx.y;
    const float* W1; const float* b1; int oc; size_t obase;
    if (h == 0)      { W1 = W1_0; b1 = b1_0; oc = 3; obase = 0; }
    else if (h == 1) { W1 = W1_1; b1 = b1_1; oc = 2; obase = 450000; }
    else if (h == 2) { W1 = W1_2; b1 = b1_2; oc = 1; obase = 750000; }
    else if (h == 3) { W1 = W1_3; b1 = b1_3; oc = 3; obase = 900000; }
    else             { W1 = W1_4; b1 = b1_4; oc = 2; obase = 1350000; }

    int tid = threadIdx.x;
    if (tid < 64) {
        int c = h * 64 + tid;
        float mean = stats[c] * (1.f / (float)NVOX);
        float var = stats[NCOL + c] * (1.f / (float)NVOX) - mean * mean;
        float inv = rsqrtf(var + 1e-5f);
        float sc = inv * gamma[c];
        sScale[tid] = sc;
        sShift[tid] = beta[c] - mean * sc;
    }
    for (int i = tid; i < 192; i += 256) {
        int cc = i / 3, jj = i - cc * 3;
        sW1[i] = (jj < oc) ? W1[cc * oc + jj] : 0.f;
    }
    if (tid == 0) {
        sB1[0] = b1[0];
        sB1[1] = (oc >= 2) ? b1[1] : 0.f;
        sB1[2] = (oc >= 3) ? b1[2] : 0.f;
    }
    __syncthreads();

    int n = (blockIdx.x * 256 + tid) * 4;    // 4 rows per thread (NVOX % 4 == 0)
    if (n >= NVOX) return;
    const unsigned short* hp = hbuf + (size_t)(h * 64) * SROW + n;
    float x[4][3];
#pragma unroll
    for (int rr = 0; rr < 4; ++rr) { x[rr][0] = sB1[0]; x[rr][1] = sB1[1]; x[rr][2] = sB1[2]; }
#pragma unroll 8
    for (int cc = 0; cc < 64; ++cc) {
        uint2 raw = *(const uint2*)(hp + (size_t)cc * SROW);   // rows n..n+3, bf16
        float sc = sScale[cc], sh = sShift[cc];
        float w0 = sW1[cc * 3 + 0], w1 = sW1[cc * 3 + 1], w2 = sW1[cc * 3 + 2];
        float v0 = __builtin_bit_cast(float, raw.x << 16);
        float v1 = __builtin_bit_cast(float, raw.x & 0xffff0000u);
        float v2 = __builtin_bit_cast(float, raw.y << 16);
        float v3 = __builtin_bit_cast(float, raw.y & 0xffff0000u);
        v0 = fmaxf(v0 * sc + sh, 0.f); v1 = fmaxf(v1 * sc + sh, 0.f);
        v2 = fmaxf(v2 * sc + sh, 0.f); v3 = fmaxf(v3 * sc + sh, 0.f);
        x[0][0] += v0 * w0; x[0][1] += v0 * w1; x[0][2] += v0 * w2;
        x[1][0] += v1 * w0; x[1][1] += v1 * w1; x[1][2] += v1 * w2;
        x[2][0] += v2 * w0; x[2][1] += v2 * w1; x[2][2] += v2 * w2;
        x[3][0] += v3 * w0; x[3][1] += v3 * w1; x[3][2] += v3 * w2;
    }
#pragma unroll
    for (int rr = 0; rr < 4; ++rr) {
        float* op = out + obase + (size_t)(n + rr) * oc;
        op[0] = x[rr][0];                 // oc is block-uniform; x indices all static
        if (oc >= 2) op[1] = x[rr][1];
        if (oc >= 3) op[2] = x[rr][2];
    }
}

extern "C" void kernel_launch(void* const* d_in, const int* in_sizes, int n_in,
                              void* d_out, int out_size, void* d_ws, size_t ws_size,
                              hipStream_t stream) {
    const float* features = (const float*)d_in[0];
    const int* nbr        = (const int*)d_in[1];
    const float* w3       = (const float*)d_in[2];
    const float* gamma    = (const float*)d_in[3];
    const float* beta     = (const float*)d_in[4];
    const float* W1_0 = (const float*)d_in[5];  const float* b1_0 = (const float*)d_in[6];
    const float* W1_1 = (const float*)d_in[7];  const float* b1_1 = (const float*)d_in[8];
    const float* W1_2 = (const float*)d_in[9];  const float* b1_2 = (const float*)d_in[10];
    const float* W1_3 = (const float*)d_in[11]; const float* b1_3 = (const float*)d_in[12];
    const float* W1_4 = (const float*)d_in[13]; const float* b1_4 = (const float*)d_in[14];
    float* out = (float*)d_out;

    char* ws = (char*)d_ws;
    unsigned short* featB = (unsigned short*)ws;               // (150000+1)*64 bf16
    unsigned short* Bt2   = (unsigned short*)(ws + 19200128);  // 5*9*8*512 bf16
    float* stats          = (float*)(ws + 19568768);           // 640 f32
    unsigned short* hbuf  = (unsigned short*)(ws + 19571328);  // col-major [320][150016]
    constexpr size_t PART_OFF = 19571328 + (size_t)NCOL * SROW * 2;  // 115581568
    float* partials = nullptr;
    if (ws_size >= PART_OFF + (size_t)MTILES * 2 * NCOL * 4)
        partials = (float*)(ws + PART_OFF);

    prep_all<<<4688 + 720, 256, 0, stream>>>(features, featB, w3, Bt2, stats);
    gemm_kernel<<<MTILES, 512, 0, stream>>>(featB, Bt2, nbr, hbuf, stats, partials);
    if (partials)
        stats_reduce<<<dim3(20, 8), 256, 0, stream>>>(partials, stats);
    head_kernel<<<dim3(147, 5), 256, 0, stream>>>(hbuf, stats, gamma, beta,
        W1_0, W1_1, W1_2, W1_3, W1_4, b1_0, b1_1, b1_2, b1_3, b1_4, out);
}

// Round 11
// 210.337 us; speedup vs baseline: 1.0666x; 1.0666x over previous
//
#include <hip/hip_runtime.h>

#define NVOX 150000
#define BM 256
#define MTILES 586          // 586*256 = 150016
#define SROW 150016         // column stride of h buffer
#define NCOL 320

typedef __attribute__((ext_vector_type(8))) short bf16x8;
typedef __attribute__((ext_vector_type(4))) float f32x4;

__device__ __forceinline__ unsigned short f2bf(float f) {
    unsigned u = __builtin_bit_cast(unsigned, f);
    u += 0x7fffu + ((u >> 16) & 1u);
    return (unsigned short)(u >> 16);
}

__device__ __forceinline__ void gld16(const void* g, void* l) {
    __builtin_amdgcn_global_load_lds(
        (const __attribute__((address_space(1))) unsigned int*)g,
        (__attribute__((address_space(3))) unsigned int*)l, 16, 0, 0);
}

// ------------- merged prep: features->bf16 + W3 repack (one launch fewer) -------------
__global__ void prep_all(const float* __restrict__ src, unsigned short* __restrict__ dst,
                         const float* __restrict__ w3, unsigned short* __restrict__ bt,
                         float* __restrict__ stats) {
    int bid = blockIdx.x, tid = threadIdx.x;
    if (bid < 4688) {                         // features f32 -> bf16, x8 vectorized
        int i = bid * 256 + tid;
        if (i < NVOX * 8) {
            const float* s = src + (size_t)i * 8;
            float4 a = *(const float4*)s;
            float4 b = *(const float4*)(s + 4);
            union { bf16x8 v; unsigned short u[8]; } r;
            r.u[0] = f2bf(a.x); r.u[1] = f2bf(a.y); r.u[2] = f2bf(a.z); r.u[3] = f2bf(a.w);
            r.u[4] = f2bf(b.x); r.u[5] = f2bf(b.y); r.u[6] = f2bf(b.z); r.u[7] = f2bf(b.w);
            *(bf16x8*)(dst + (size_t)i * 8) = r.v;
        } else if (i < NVOX * 8 + 8) {        // zero row for invalid/pad gathers
            bf16x8 z = {0, 0, 0, 0, 0, 0, 0, 0};
            *(bf16x8*)(dst + (size_t)i * 8) = z;
        }
    } else {                                  // W3 -> chunk-major bf16 (+ stats zero)
        int i = (bid - 4688) * 256 + tid;     // exactly 184320 threads
        int h = i / 36864;
        int rem = i - h * 36864;
        int kk = rem >> 12;
        int c = (rem >> 6) & 63;
        int o = rem & 63;
        bt[(size_t)(((h * 9 + kk) * 8) + (c >> 3)) * 512 + o * 8 + (c & 7)] = f2bf(w3[i]);
        if (i < 2 * NCOL) stats[i] = 0.f;
    }
}

// ---------------- gather-GEMM: BM=256 — AMORTIZE the fixed per-phase overhead ---------
// R0-R10 invariant: per-K-step cost ~4.8-5.0k cyc/CU of which only ~1.55k is MFMA; the
// ~3.3k skeleton (stage issue + gather service + vmcnt + barrier) never moved under any
// traffic/pipeline/placement change. So amortize: BM=256 doubles MFMA per phase
// (640/CU ~3.1k cyc) with the SAME per-phase skeleton (9 vm ops/wave, one barrier pair,
// depth-1 vmcnt(9)). Core otherwise bit-identical to R9's measured-best (85-87us).
// LDS: sA 2x32K @0, sB 2x40K @65536, idx @147456 (9216B) -> 156672, 1 blk/CU (8 waves).
__global__ __launch_bounds__(512, 2)
void gemm_kernel(const unsigned short* __restrict__ featB,
                 const unsigned short* __restrict__ Bt2,
                 const int* __restrict__ nbr,
                 unsigned short* __restrict__ hbuf,
                 float* __restrict__ stats,
                 float* __restrict__ partials) {
    __shared__ __align__(16) char smem[156672];
    constexpr int SB_OFF = 65536;    // B dbuf 2x40960
    constexpr int IDX_OFF = 147456;  // 9*256 int byte-offsets (9216 B)
    constexpr int SRED_OFF = 88064;  // stats staging 640*8 B (dead sB area, >87040)

    int mtile = blockIdx.x;
    int m0 = mtile * BM;

    int tid = threadIdx.x;
    int w = tid >> 6, lane = tid & 63;
    int quad = lane >> 4, m16 = lane & 15;

    // ---- stage neighbor byte-offset table: sIdx[kk][row] = srow*128 ----
    for (int lin = tid; lin < BM * 9; lin += 512) {
        int row = lin / 9, kkq = lin - row * 9;
        int v = -1;
        if (m0 + row < NVOX) v = nbr[(size_t)(m0 + row) * 9 + kkq];
        *(int*)(smem + IDX_OFF + (kkq * BM + row) * 4) = ((v < 0) ? NVOX : v) * 128;
    }
    __syncthreads();

    f32x4 acc[8][5];
#pragma unroll
    for (int mt = 0; mt < 8; ++mt)
#pragma unroll
        for (int nt = 0; nt < 5; ++nt)
            acc[mt][nt] = (f32x4){0.f, 0.f, 0.f, 0.f};

    const char* fb = (const char*)featB;
    const char* bt = (const char*)Bt2;

    int half = w >> 2;           // wave's 128-row half (0/1)
    int mrow = half * 128;
    int cbase = (w & 3) * 80;    // wave's 80-col quarter of the 320 cols

    // gather geometry: 8 lanes per row; lane = rloc*8 + j
    int rloc = lane >> 3, j = lane & 7;
    int jx = (j ^ rloc) * 16;    // source-chunk XOR swizzle ((row&7) == rloc)

    // B stage units for this wave: u = w*5+j -> (head, c16); 8 waves x 5 = 40 KB/kk
    int bsj[5], bdj[5];
#pragma unroll
    for (int jj = 0; jj < 5; ++jj) {
        int u = w * 5 + jj;
        int h = u >> 3, c16 = u & 7;
        bsj[jj] = (h * 72 + c16) * 1024 + lane * 16;  // + kk*8192 per tile
        bdj[jj] = (h * 8 + c16) * 1024;
    }
    // per-lane B-frag byte offsets within sB: col -> (head, o) chunk-major
    int sBoff[5];
#pragma unroll
    for (int nt = 0; nt < 5; ++nt) {
        int c = cbase + nt * 16 + m16;
        sBoff[nt] = (c >> 6) * 8192 + (c & 63) * 16;
    }
    int axor = m16 & 7;          // == row & 7 for all frag rows

    auto stageA = [&](int buf, int kk) {       // wave w stages rows w*32..w*32+31
        char* sA = smem + buf * 32768;
#pragma unroll
        for (int i = 0; i < 4; ++i) {
            int off = *(const int*)(smem + IDX_OFF + (kk * BM + w * 32 + i * 8 + rloc) * 4);
            gld16(fb + off + jx, sA + w * 4096 + i * 1024);   // 8 full rows/instr
        }
    };
    auto stageB = [&](int buf, int kk) {
        char* sB = smem + SB_OFF + buf * 40960;
#pragma unroll
        for (int jj = 0; jj < 5; ++jj)         // 5 ops, L2-hot sequential
            gld16(bt + (size_t)(bsj[jj] + kk * 8192), sB + bdj[jj]);
    };

    // prologue: tile 0 -> 9 vm ops in flight
    stageA(0, 0);
    stageB(0, 0);

#pragma unroll
    for (int kk = 0; kk < 9; ++kk) {
        const int p = kk & 1;
        if (kk < 8) {
            stageA(p ^ 1, kk + 1);             // 4 vm ops
            stageB(p ^ 1, kk + 1);             // 5 vm ops (18 in flight)
            asm volatile("s_waitcnt vmcnt(9)" ::: "memory");  // tile kk retired
        } else {
            asm volatile("s_waitcnt vmcnt(0)" ::: "memory");
        }
        asm volatile("s_barrier" ::: "memory");        // raw barrier: NO drain
        __builtin_amdgcn_sched_barrier(0);             // rule 18: pin ds_read/MFMA below
        __builtin_amdgcn_s_setprio(1);
        const char* sA = smem + p * 32768;
        const char* sB = smem + SB_OFF + p * 40960;
#pragma unroll
        for (int ks = 0; ks < 2; ++ks) {
            bf16x8 af[8], bf[5];
            int xq = ((ks * 4 + quad) ^ axor) * 16;    // swizzled chunk within row
#pragma unroll
            for (int mt = 0; mt < 8; ++mt)
                af[mt] = *(const bf16x8*)(sA + (mrow + mt * 16 + m16) * 128 + xq);
#pragma unroll
            for (int nt = 0; nt < 5; ++nt)
                bf[nt] = *(const bf16x8*)(sB + sBoff[nt] + (ks * 4 + quad) * 1024);
#pragma unroll
            for (int mt = 0; mt < 8; ++mt)
#pragma unroll
                for (int nt = 0; nt < 5; ++nt)
                    acc[mt][nt] = __builtin_amdgcn_mfma_f32_16x16x32_bf16(
                        af[mt], bf[nt], acc[mt][nt], 0, 0, 0);
        }
        __builtin_amdgcn_s_setprio(0);
        __builtin_amdgcn_sched_barrier(0);
        asm volatile("s_barrier" ::: "memory");        // buffers free to restage
    }
    __builtin_amdgcn_sched_barrier(0);   // keep epilogue out of the loop region

    // ---- epilogue 1: transpose in TWO 128-row passes (region [0,87040) reused) ----
#pragma unroll
    for (int pass = 0; pass < 2; ++pass) {
        if (half == pass) {                    // wave-uniform branch
#pragma unroll
            for (int mt = 0; mt < 8; ++mt) {
#pragma unroll
                for (int nt = 0; nt < 5; ++nt) {
                    int col = cbase + nt * 16 + m16;
                    int row = mt * 16 + quad * 4;      // local row within the 128
                    f32x4 v = acc[mt][nt];
                    unsigned lo = (unsigned)f2bf(v.x) | ((unsigned)f2bf(v.y) << 16);
                    unsigned hi = (unsigned)f2bf(v.z) | ((unsigned)f2bf(v.w) << 16);
                    uint2 pk; pk.x = lo; pk.y = hi;
                    *(uint2*)(smem + col * 272 + row * 2) = pk;
                }
            }
        }
        __syncthreads();
#pragma unroll
        for (int it = 0; it < 20; ++it) {      // 320 cols x 256B, 4KB contiguous/iter
            int col = it * 16 + (tid >> 5);
            int l32 = tid & 31;
            uint2 v = *(const uint2*)(smem + col * 272 + l32 * 8);
            *(uint2*)(hbuf + (size_t)col * SROW + m0 + pass * 128 + l32 * 4) = v;
        }
        __syncthreads();
    }

    // ---- epilogue 2: BN statistics (pad/invalid rows are exact zeros) ----
    float s[5], ss[5];
#pragma unroll
    for (int nt = 0; nt < 5; ++nt) {
        float a = 0.f, b = 0.f;
#pragma unroll
        for (int mt = 0; mt < 8; ++mt) {
            f32x4 v = acc[mt][nt];
            a += v.x + v.y + v.z + v.w;
            b += v.x * v.x + v.y * v.y + v.z * v.z + v.w * v.w;
        }
        s[nt] = a; ss[nt] = b;
        s[nt] += __shfl_xor(s[nt], 16); s[nt] += __shfl_xor(s[nt], 32);
        ss[nt] += __shfl_xor(ss[nt], 16); ss[nt] += __shfl_xor(ss[nt], 32);
    }
    if (quad == 0) {   // SRED (88064+, dead sB) disjoint from transpose (<87040)
#pragma unroll
        for (int nt = 0; nt < 5; ++nt) {
            float* p = (float*)(smem + SRED_OFF + (w * 80 + nt * 16 + m16) * 8);
            p[0] = s[nt]; p[1] = ss[nt];
        }
    }
    __syncthreads();
    if (tid < NCOL) {
        int c = tid;
        int qq = c / 80, lc = c - qq * 80;   // waves qq (rows 0-127) and qq+4 (128-255)
        const float* p0 = (const float*)(smem + SRED_OFF + (qq * 80 + lc) * 8);
        const float* p1 = (const float*)(smem + SRED_OFF + ((qq + 4) * 80 + lc) * 8);
        float vsum = p0[0] + p1[0];
        float vss  = p0[1] + p1[1];
        if (partials) {
            float* pp = partials + (size_t)mtile * (2 * NCOL);
            pp[c] = vsum;                // coalesced, no atomics
            pp[NCOL + c] = vss;
        } else {
            atomicAdd(&stats[c], vsum);
            atomicAdd(&stats[NCOL + c], vss);
        }
    }
}

// ---- stats_reduce: wide (160 blocks), coalesced reads, spread atomics ----
__global__ __launch_bounds__(256)
void stats_reduce(const float* __restrict__ partials, float* __restrict__ stats) {
    __shared__ float red[256];
    int tid = threadIdx.x;
    int cl = tid & 31, sc = tid >> 5;
    int jcol = blockIdx.x * 32 + cl;
    int ybase = blockIdx.y * 74;             // 8*74 >= 586
    int mhi = ybase + 74; if (mhi > MTILES) mhi = MTILES;
    int mlo = ybase + sc * 10;               // 8*10 >= 74
    int mend = mlo + 10; if (mend > mhi) mend = mhi;
    float s = 0.f;
    for (int m = mlo; m < mend; ++m)
        s += partials[(size_t)m * (2 * NCOL) + jcol];
    red[tid] = s;
    __syncthreads();
    if (tid < 32) {
        float a = red[tid];
#pragma unroll
        for (int k = 1; k < 8; ++k) a += red[k * 32 + tid];
        atomicAdd(&stats[blockIdx.x * 32 + tid], a);
    }
}

// ------- pass 2: BN + ReLU + 1x1 conv (best measured head: 4 rows/thread, coalesced
// 512B/wave-instr reads of column-major hbuf, per-head grid)
__global__ __launch_bounds__(256)
void head_kernel(const unsigned short* __restrict__ hbuf,
                 const float* __restrict__ stats,
                 const float* __restrict__ gamma, const float* __restrict__ beta,
                 const float* __restrict__ W1_0, const float* __restrict__ W1_1,
                 const float* __restrict__ W1_2, const float* __restrict__ W1_3,
                 const float* __restrict__ W1_4,
                 const float* __restrict__ b1_0, const float* __restrict__ b1_1,
                 const float* __restrict__ b1_2, const float* __restrict__ b1_3,
                 const float* __restrict__ b1_4,
                 float* __restrict__ out) {
    __shared__ float sScale[64], sShift[64], sW1[192], sB1[3];
    int h = blockIdx.y;
    const float* W1; const float* b1; int oc; size_t obase;
    if (h == 0)      { W1 = W1_0; b1 = b1_0; oc = 3; obase = 0; }
    else if (h == 1) { W1 = W1_1; b1 = b1_1; oc = 2; obase = 450000; }
    else if (h == 2) { W1 = W1_2; b1 = b1_2; oc = 1; obase = 750000; }
    else if (h == 3) { W1 = W1_3; b1 = b1_3; oc = 3; obase = 900000; }
    else             { W1 = W1_4; b1 = b1_4; oc = 2; obase = 1350000; }

    int tid = threadIdx.x;
    if (tid < 64) {
        int c = h * 64 + tid;
        float mean = stats[c] * (1.f / (float)NVOX);
        float var = stats[NCOL + c] * (1.f / (float)NVOX) - mean * mean;
        float inv = rsqrtf(var + 1e-5f);
        float sc = inv * gamma[c];
        sScale[tid] = sc;
        sShift[tid] = beta[c] - mean * sc;
    }
    for (int i = tid; i < 192; i += 256) {
        int cc = i / 3, jj = i - cc * 3;
        sW1[i] = (jj < oc) ? W1[cc * oc + jj] : 0.f;
    }
    if (tid == 0) {
        sB1[0] = b1[0];
        sB1[1] = (oc >= 2) ? b1[1] : 0.f;
        sB1[2] = (oc >= 3) ? b1[2] : 0.f;
    }
    __syncthreads();

    int n = (blockIdx.x * 256 + tid) * 4;    // 4 rows per thread (NVOX % 4 == 0)
    if (n >= NVOX) return;
    const unsigned short* hp = hbuf + (size_t)(h * 64) * SROW + n;
    float x[4][3];
#pragma unroll
    for (int rr = 0; rr < 4; ++rr) { x[rr][0] = sB1[0]; x[rr][1] = sB1[1]; x[rr][2] = sB1[2]; }
#pragma unroll 8
    for (int cc = 0; cc < 64; ++cc) {
        uint2 raw = *(const uint2*)(hp + (size_t)cc * SROW);   // rows n..n+3, bf16
        float sc = sScale[cc], sh = sShift[cc];
        float w0 = sW1[cc * 3 + 0], w1 = sW1[cc * 3 + 1], w2 = sW1[cc * 3 + 2];
        float v0 = __builtin_bit_cast(float, raw.x << 16);
        float v1 = __builtin_bit_cast(float, raw.x & 0xffff0000u);
        float v2 = __builtin_bit_cast(float, raw.y << 16);
        float v3 = __builtin_bit_cast(float, raw.y & 0xffff0000u);
        v0 = fmaxf(v0 * sc + sh, 0.f); v1 = fmaxf(v1 * sc + sh, 0.f);
        v2 = fmaxf(v2 * sc + sh, 0.f); v3 = fmaxf(v3 * sc + sh, 0.f);
        x[0][0] += v0 * w0; x[0][1] += v0 * w1; x[0][2] += v0 * w2;
        x[1][0] += v1 * w0; x[1][1] += v1 * w1; x[1][2] += v1 * w2;
        x[2][0] += v2 * w0; x[2][1] += v2 * w1; x[2][2] += v2 * w2;
        x[3][0] += v3 * w0; x[3][1] += v3 * w1; x[3][2] += v3 * w2;
    }
#pragma unroll
    for (int rr = 0; rr < 4; ++rr) {
        float* op = out + obase + (size_t)(n + rr) * oc;
        op[0] = x[rr][0];                 // oc is block-uniform; x indices all static
        if (oc >= 2) op[1] = x[rr][1];
        if (oc >= 3) op[2] = x[rr][2];
    }
}

extern "C" void kernel_launch(void* const* d_in, const int* in_sizes, int n_in,
                              void* d_out, int out_size, void* d_ws, size_t ws_size,
                              hipStream_t stream) {
    const float* features = (const float*)d_in[0];
    const int* nbr        = (const int*)d_in[1];
    const float* w3       = (const float*)d_in[2];
    const float* gamma    = (const float*)d_in[3];
    const float* beta     = (const float*)d_in[4];
    const float* W1_0 = (const float*)d_in[5];  const float* b1_0 = (const float*)d_in[6];
    const float* W1_1 = (const float*)d_in[7];  const float* b1_1 = (const float*)d_in[8];
    const float* W1_2 = (const float*)d_in[9];  const float* b1_2 = (const float*)d_in[10];
    const float* W1_3 = (const float*)d_in[11]; const float* b1_3 = (const float*)d_in[12];
    const float* W1_4 = (const float*)d_in[13]; const float* b1_4 = (const float*)d_in[14];
    float* out = (float*)d_out;

    char* ws = (char*)d_ws;
    unsigned short* featB = (unsigned short*)ws;               // (150000+1)*64 bf16
    unsigned short* Bt2   = (unsigned short*)(ws + 19200128);  // 5*9*8*512 bf16
    float* stats          = (float*)(ws + 19568768);           // 640 f32
    unsigned short* hbuf  = (unsigned short*)(ws + 19571328);  // col-major [320][150016]
    constexpr size_t PART_OFF = 19571328 + (size_t)NCOL * SROW * 2;  // 115581568
    float* partials = nullptr;
    if (ws_size >= PART_OFF + (size_t)MTILES * 2 * NCOL * 4)
        partials = (float*)(ws + PART_OFF);

    prep_all<<<4688 + 720, 256, 0, stream>>>(features, featB, w3, Bt2, stats);
    gemm_kernel<<<MTILES, 512, 0, stream>>>(featB, Bt2, nbr, hbuf, stats, partials);
    if (partials)
        stats_reduce<<<dim3(20, 8), 256, 0, stream>>>(partials, stats);
    head_kernel<<<dim3(147, 5), 256, 0, stream>>>(hbuf, stats, gamma, beta,
        W1_0, W1_1, W1_2, W1_3, W1_4, b1_0, b1_1, b1_2, b1_3, b1_4, out);
}